// Round 1
// baseline (313.611 us; speedup 1.0000x reference)
//
#include <hip/hip_runtime.h>
#include <hip/hip_bf16.h>
#include <cstdint>
#include <cstddef>

#define K_DIM 4096

typedef __bf16 bf16x8 __attribute__((ext_vector_type(8)));
typedef float  f32x4  __attribute__((ext_vector_type(4)));
typedef unsigned short ushort8 __attribute__((ext_vector_type(8)));

struct KronPtrs { const float* a[8]; const float* b[8]; };

// ---------------------------------------------------------------------------
// Kernel 1: W[p][q] = (1/(2*sqrt(8))) * sum_k a_k[p/mb, q/mb] * b_k[p%mb, q%mb]
// Each thread produces 8 consecutive q (one 16B bf16 store). Since q0 is
// 8-aligned and all mb >= 8, q/mb is constant across the 8 -> 1 a-load +
// 8 contiguous b-loads (2x float4) per term.
// ---------------------------------------------------------------------------
__global__ __launch_bounds__(256) void build_w_kernel(KronPtrs P,
                                                      __hip_bfloat16* __restrict__ Wb)
{
    const int t   = blockIdx.x * 256 + threadIdx.x;   // 2M threads
    const int row = t >> 9;                           // 0..4095
    const int q0  = (t & 511) << 3;                   // 0..4088 step 8

    float acc[8] = {0.f,0.f,0.f,0.f,0.f,0.f,0.f,0.f};

#define KTERM(IDX, MA, LB)                                                     \
    {                                                                          \
        const int mb_   = 1 << (LB);                                           \
        const float av  = P.a[IDX][(row >> (LB)) * (MA) + (q0 >> (LB))];       \
        const float* bp = P.b[IDX] + (row & (mb_ - 1)) * mb_ + (q0 & (mb_ - 1)); \
        const float4 x0 = *(const float4*)(bp);                                \
        const float4 x1 = *(const float4*)(bp + 4);                            \
        acc[0] += av * x0.x; acc[1] += av * x0.y;                              \
        acc[2] += av * x0.z; acc[3] += av * x0.w;                              \
        acc[4] += av * x1.x; acc[5] += av * x1.y;                              \
        acc[6] += av * x1.z; acc[7] += av * x1.w;                              \
    }

    KTERM(0,  64, 6)
    KTERM(1,  64, 6)
    KTERM(2,  32, 7)
    KTERM(3, 128, 5)
    KTERM(4,  16, 8)
    KTERM(5, 256, 4)
    KTERM(6,   8, 9)
    KTERM(7, 512, 3)
#undef KTERM

    const float s = 0.17677669529663687f;  // 1 / (2*sqrt(8))
    union { __hip_bfloat16 h[8]; ushort8 v; } u;
#pragma unroll
    for (int i = 0; i < 8; ++i) u.h[i] = __float2bfloat16(acc[i] * s);
    *(ushort8*)(void*)(Wb + (size_t)row * K_DIM + q0) = u.v;
}

// ---------------------------------------------------------------------------
// Kernel 2: x fp32 -> bf16
// ---------------------------------------------------------------------------
__global__ __launch_bounds__(256) void cvt_x_kernel(const float* __restrict__ x,
                                                    __hip_bfloat16* __restrict__ Xb)
{
    const size_t t = (size_t)blockIdx.x * 256 + threadIdx.x;
    const size_t o = t * 8;
    const float4 v0 = *(const float4*)(x + o);
    const float4 v1 = *(const float4*)(x + o + 4);
    union { __hip_bfloat16 h[8]; ushort8 v; } u;
    u.h[0] = __float2bfloat16(v0.x);
    u.h[1] = __float2bfloat16(v0.y);
    u.h[2] = __float2bfloat16(v0.z);
    u.h[3] = __float2bfloat16(v0.w);
    u.h[4] = __float2bfloat16(v1.x);
    u.h[5] = __float2bfloat16(v1.y);
    u.h[6] = __float2bfloat16(v1.z);
    u.h[7] = __float2bfloat16(v1.w);
    *(ushort8*)(void*)(Xb + o) = u.v;
}

// ---------------------------------------------------------------------------
// Kernel 3: C[m][n] = sum_k Wb[m][k] * Xb[n][k] + bias[n]   (C = W @ X^T)
// 128x128 block tile, 4 waves (2x2), each wave 64x64 via 4x4 mfma 16x16x32.
// BK=64, global_load_lds width=16 staging, XOR chunk swizzle for LDS reads.
// ---------------------------------------------------------------------------
__device__ __forceinline__ void gload_lds16(const void* g, void* l)
{
    __builtin_amdgcn_global_load_lds((const __attribute__((address_space(1))) void*)g,
                                     (__attribute__((address_space(3))) void*)l,
                                     16, 0, 0);
}

__global__ __launch_bounds__(256) void gemm_kernel(
        const __hip_bfloat16* __restrict__ Wb,
        const __hip_bfloat16* __restrict__ Xb,
        const float* __restrict__ bias,
        float* __restrict__ C)
{
    __shared__ __align__(16) __hip_bfloat16 lsA[128 * 64];
    __shared__ __align__(16) __hip_bfloat16 lsB[128 * 64];

    const int tid  = threadIdx.x;
    const int lane = tid & 63;
    const int wid  = tid >> 6;
    const int wr   = wid >> 1;   // wave row 0..1
    const int wc   = wid & 1;    // wave col 0..1

    const int bm = blockIdx.y << 7;
    const int bn = blockIdx.x << 7;

    // Staging: LDS dest = wave-uniform base + lane*16B.  Within a 1KB chunk
    // (8 rows x 128B), lane L -> row L>>3, physical 16B-chunk L&7.  Physical
    // chunk p of row r holds LOGICAL chunk p ^ (r&7)  (bank-conflict swizzle),
    // so lane L fetches global k-offset ((L&7)^(L>>3))*8.
    const int sr = lane >> 3;        // row within 8-row chunk
    const int lc = (lane & 7) ^ sr;  // logical chunk this lane fetches

    const __hip_bfloat16* gA0 = Wb + (size_t)(bm + sr) * K_DIM + lc * 8;
    const __hip_bfloat16* gB0 = Xb + (size_t)(bn + sr) * K_DIM + lc * 8;

    f32x4 acc[4][4];
#pragma unroll
    for (int i = 0; i < 4; ++i)
#pragma unroll
        for (int j = 0; j < 4; ++j) acc[i][j] = (f32x4)(0.0f);

    const int fr = lane & 15;   // fragment row (m or n within 16x16 tile)
    const int fq = lane >> 4;   // quad 0..3
    const int fx = lane & 7;    // read-side swizzle xor (= row&7 of frag rows)

    for (int k0 = 0; k0 < K_DIM; k0 += 64) {
#pragma unroll
        for (int i = 0; i < 4; ++i) {
            const int c = (wid << 2) + i;             // chunk 0..15
            gload_lds16(gA0 + (size_t)(c * 8) * K_DIM + k0, lsA + c * 512);
            gload_lds16(gB0 + (size_t)(c * 8) * K_DIM + k0, lsB + c * 512);
        }
        __syncthreads();  // compiler emits s_waitcnt vmcnt(0) before s_barrier

#pragma unroll
        for (int kk = 0; kk < 2; ++kk) {
            const int lch = (kk << 2) + fq;   // logical k-chunk 0..7
            const int pch = lch ^ fx;         // physical chunk in LDS row
            bf16x8 af[4], bfr[4];
#pragma unroll
            for (int mi = 0; mi < 4; ++mi) {
                const int r = (wr << 6) + (mi << 4) + fr;
                af[mi] = *(const bf16x8*)(const void*)(lsA + r * 64 + pch * 8);
            }
#pragma unroll
            for (int ni = 0; ni < 4; ++ni) {
                const int r = (wc << 6) + (ni << 4) + fr;
                bfr[ni] = *(const bf16x8*)(const void*)(lsB + r * 64 + pch * 8);
            }
#pragma unroll
            for (int mi = 0; mi < 4; ++mi)
#pragma unroll
                for (int ni = 0; ni < 4; ++ni)
                    acc[mi][ni] = __builtin_amdgcn_mfma_f32_16x16x32_bf16(
                        af[mi], bfr[ni], acc[mi][ni], 0, 0, 0);
        }
        __syncthreads();
    }

    // Epilogue: C/D layout col = lane&15, row = (lane>>4)*4 + reg
#pragma unroll
    for (int ni = 0; ni < 4; ++ni) {
        const int col = bn + (wc << 6) + (ni << 4) + fr;
        const float bv = bias[col];
#pragma unroll
        for (int mi = 0; mi < 4; ++mi) {
            const int r0 = bm + (wr << 6) + (mi << 4) + (fq << 2);
#pragma unroll
            for (int i = 0; i < 4; ++i)
                C[(size_t)(r0 + i) * K_DIM + col] = acc[mi][ni][i] + bv;
        }
    }
}

// ---------------------------------------------------------------------------
extern "C" void kernel_launch(void* const* d_in, const int* in_sizes, int n_in,
                              void* d_out, int out_size, void* d_ws, size_t ws_size,
                              hipStream_t stream)
{
    (void)in_sizes; (void)n_in; (void)out_size; (void)ws_size;

    const float* x    = (const float*)d_in[0];
    KronPtrs P;
    for (int i = 0; i < 8; ++i) {
        P.a[i] = (const float*)d_in[1 + i];
        P.b[i] = (const float*)d_in[9 + i];
    }
    const float* bias = (const float*)d_in[17];

    __hip_bfloat16* Wb = (__hip_bfloat16*)d_ws;                               // 32 MiB
    __hip_bfloat16* Xb = (__hip_bfloat16*)((char*)d_ws +
                          (size_t)K_DIM * K_DIM * sizeof(__hip_bfloat16));    // 32 MiB
    float* y = (float*)d_out;

    build_w_kernel<<<8192, 256, 0, stream>>>(P, Wb);
    cvt_x_kernel<<<8192, 256, 0, stream>>>(x, Xb);

    dim3 grid(32, 32);
    gemm_kernel<<<grid, 256, 0, stream>>>(Wb, Xb, bias, y);
}

// Round 2
// 303.773 us; speedup vs baseline: 1.0324x; 1.0324x over previous
//
#include <hip/hip_runtime.h>
#include <hip/hip_bf16.h>
#include <cstdint>
#include <cstddef>

#define K_DIM 4096

typedef __bf16 bf16x8 __attribute__((ext_vector_type(8)));
typedef float  f32x4  __attribute__((ext_vector_type(4)));
typedef unsigned short ushort8 __attribute__((ext_vector_type(8)));

struct KronPtrs { const float* a[8]; const float* b[8]; };

// ---------------------------------------------------------------------------
// Fused prologue.
//   Blocks [0, 8192):      x fp32 -> bf16   (8 elems / thread)
//   Blocks [8192, 12288):  build one row of W = sum_k kron(a_k,b_k) * s
// build_w strategy: stage the 8 a-row slices (sum ma = 1080 floats) and the
// 8 b-row slices (sum mb = 1080 floats) this row needs into LDS once, then
// each thread computes 16 columns purely from LDS (broadcast / 2-way access
// patterns, conflict-free) and issues two coalesced 16B stores. This removes
// the 512 MB of L1/L2 gather traffic of the previous per-thread version and
// makes build_w write-bound (~32 MB).
// ---------------------------------------------------------------------------
__global__ __launch_bounds__(256) void prologue_kernel(
        KronPtrs P,
        const float* __restrict__ x,
        __hip_bfloat16* __restrict__ Wb,
        __hip_bfloat16* __restrict__ Xb)
{
    __shared__ __align__(16) float sa[1080];
    __shared__ __align__(16) float sb[1080];

    const int tid = threadIdx.x;

    if (blockIdx.x < 8192) {
        // ---------------- x convert ----------------
        const size_t t = (size_t)blockIdx.x * 256 + tid;
        const size_t o = t * 8;
        const float4 v0 = *(const float4*)(x + o);
        const float4 v1 = *(const float4*)(x + o + 4);
        union { __hip_bfloat16 h[8]; ushort8 v; } u;
        u.h[0] = __float2bfloat16(v0.x);
        u.h[1] = __float2bfloat16(v0.y);
        u.h[2] = __float2bfloat16(v0.z);
        u.h[3] = __float2bfloat16(v0.w);
        u.h[4] = __float2bfloat16(v1.x);
        u.h[5] = __float2bfloat16(v1.y);
        u.h[6] = __float2bfloat16(v1.z);
        u.h[7] = __float2bfloat16(v1.w);
        *(ushort8*)(void*)(Xb + o) = u.v;
        return;
    }

    // ---------------- build one row of W ----------------
    const int row = blockIdx.x - 8192;

    // term:        0    1    2    3    4    5    6    7
    // ma:         64   64   32  128   16  256    8  512
    // mb:         64   64  128   32  256   16  512    8   (mb = 1<<LB)
    // offa:        0   64  128  160  288  304  560  568   (total 1080)
    // offb:        0   64  128  256  288  544  560 1072   (total 1080)

#define STAGE(IDX, MA, LB, OA, OB)                                             \
    {                                                                          \
        const int mb_ = 1 << (LB);                                             \
        const float* ap = P.a[IDX] + (size_t)(row >> (LB)) * (MA);             \
        const float* bp = P.b[IDX] + (size_t)(row & (mb_ - 1)) * mb_;          \
        for (int i = tid; i < (MA); i += 256) sa[(OA) + i] = ap[i];            \
        for (int i = tid; i < mb_;  i += 256) sb[(OB) + i] = bp[i];            \
    }

    STAGE(0,  64, 6,   0,    0)
    STAGE(1,  64, 6,  64,   64)
    STAGE(2,  32, 7, 128,  128)
    STAGE(3, 128, 5, 160,  256)
    STAGE(4,  16, 8, 288,  288)
    STAGE(5, 256, 4, 304,  544)
    STAGE(6,   8, 9, 560,  560)
    STAGE(7, 512, 3, 568, 1072)
#undef STAGE

    __syncthreads();

    const float s = 0.17677669529663687f;  // 1 / (2*sqrt(8))
    const int q0 = tid << 4;               // 16 columns per thread

#pragma unroll
    for (int g = 0; g < 2; ++g) {
        const int q8 = q0 + (g << 3);      // 8-aligned column group
        float acc[8] = {0.f,0.f,0.f,0.f,0.f,0.f,0.f,0.f};

#define KTERM(LB, OA, OB)                                                      \
    {                                                                          \
        const int mb_   = 1 << (LB);                                           \
        const float av  = sa[(OA) + (q8 >> (LB))];                             \
        const float* bp = sb + (OB) + (q8 & (mb_ - 1));                        \
        const float4 x0 = *(const float4*)(bp);                                \
        const float4 x1 = *(const float4*)(bp + 4);                            \
        acc[0] += av * x0.x; acc[1] += av * x0.y;                              \
        acc[2] += av * x0.z; acc[3] += av * x0.w;                              \
        acc[4] += av * x1.x; acc[5] += av * x1.y;                              \
        acc[6] += av * x1.z; acc[7] += av * x1.w;                              \
    }

        KTERM(6,   0,    0)
        KTERM(6,  64,   64)
        KTERM(7, 128,  128)
        KTERM(5, 160,  256)
        KTERM(8, 288,  288)
        KTERM(4, 304,  544)
        KTERM(9, 560,  560)
        KTERM(3, 568, 1072)
#undef KTERM

        union { __hip_bfloat16 h[8]; ushort8 v; } u;
#pragma unroll
        for (int i = 0; i < 8; ++i) u.h[i] = __float2bfloat16(acc[i] * s);
        *(ushort8*)(void*)(Wb + (size_t)row * K_DIM + q8) = u.v;
    }
}

// ---------------------------------------------------------------------------
// GEMM: C[m][n] = sum_k Wb[m][k] * Xb[n][k] + bias[n]   (C = W @ X^T)
// 128x128 block tile, 4 waves (2x2), each wave 64x64 via 4x4 mfma 16x16x32.
// BK=64, global_load_lds width=16 staging, XOR chunk swizzle for LDS reads.
// Unchanged from R1 (792 TF; at the m97-structure plateau).
// ---------------------------------------------------------------------------
__device__ __forceinline__ void gload_lds16(const void* g, void* l)
{
    __builtin_amdgcn_global_load_lds((const __attribute__((address_space(1))) void*)g,
                                     (__attribute__((address_space(3))) void*)l,
                                     16, 0, 0);
}

__global__ __launch_bounds__(256) void gemm_kernel(
        const __hip_bfloat16* __restrict__ Wb,
        const __hip_bfloat16* __restrict__ Xb,
        const float* __restrict__ bias,
        float* __restrict__ C)
{
    __shared__ __align__(16) __hip_bfloat16 lsA[128 * 64];
    __shared__ __align__(16) __hip_bfloat16 lsB[128 * 64];

    const int tid  = threadIdx.x;
    const int lane = tid & 63;
    const int wid  = tid >> 6;
    const int wr   = wid >> 1;   // wave row 0..1
    const int wc   = wid & 1;    // wave col 0..1

    const int bm = blockIdx.y << 7;
    const int bn = blockIdx.x << 7;

    // Staging: LDS dest = wave-uniform base + lane*16B.  Within a 1KB chunk
    // (8 rows x 128B), lane L -> row L>>3, physical 16B-chunk L&7.  Physical
    // chunk p of row r holds LOGICAL chunk p ^ (r&7)  (bank-conflict swizzle),
    // so lane L fetches global k-offset ((L&7)^(L>>3))*8.
    const int sr = lane >> 3;        // row within 8-row chunk
    const int lc = (lane & 7) ^ sr;  // logical chunk this lane fetches

    const __hip_bfloat16* gA0 = Wb + (size_t)(bm + sr) * K_DIM + lc * 8;
    const __hip_bfloat16* gB0 = Xb + (size_t)(bn + sr) * K_DIM + lc * 8;

    f32x4 acc[4][4];
#pragma unroll
    for (int i = 0; i < 4; ++i)
#pragma unroll
        for (int j = 0; j < 4; ++j) acc[i][j] = (f32x4)(0.0f);

    const int fr = lane & 15;   // fragment row (m or n within 16x16 tile)
    const int fq = lane >> 4;   // quad 0..3
    const int fx = lane & 7;    // read-side swizzle xor (= row&7 of frag rows)

    for (int k0 = 0; k0 < K_DIM; k0 += 64) {
#pragma unroll
        for (int i = 0; i < 4; ++i) {
            const int c = (wid << 2) + i;             // chunk 0..15
            gload_lds16(gA0 + (size_t)(c * 8) * K_DIM + k0, lsA + c * 512);
            gload_lds16(gB0 + (size_t)(c * 8) * K_DIM + k0, lsB + c * 512);
        }
        __syncthreads();  // compiler emits s_waitcnt vmcnt(0) before s_barrier

#pragma unroll
        for (int kk = 0; kk < 2; ++kk) {
            const int lch = (kk << 2) + fq;   // logical k-chunk 0..7
            const int pch = lch ^ fx;         // physical chunk in LDS row
            bf16x8 af[4], bfr[4];
#pragma unroll
            for (int mi = 0; mi < 4; ++mi) {
                const int r = (wr << 6) + (mi << 4) + fr;
                af[mi] = *(const bf16x8*)(const void*)(lsA + r * 64 + pch * 8);
            }
#pragma unroll
            for (int ni = 0; ni < 4; ++ni) {
                const int r = (wc << 6) + (ni << 4) + fr;
                bfr[ni] = *(const bf16x8*)(const void*)(lsB + r * 64 + pch * 8);
            }
#pragma unroll
            for (int mi = 0; mi < 4; ++mi)
#pragma unroll
                for (int ni = 0; ni < 4; ++ni)
                    acc[mi][ni] = __builtin_amdgcn_mfma_f32_16x16x32_bf16(
                        af[mi], bfr[ni], acc[mi][ni], 0, 0, 0);
        }
        __syncthreads();
    }

    // Epilogue: C/D layout col = lane&15, row = (lane>>4)*4 + reg
#pragma unroll
    for (int ni = 0; ni < 4; ++ni) {
        const int col = bn + (wc << 6) + (ni << 4) + fr;
        const float bv = bias[col];
#pragma unroll
        for (int mi = 0; mi < 4; ++mi) {
            const int r0 = bm + (wr << 6) + (mi << 4) + (fq << 2);
#pragma unroll
            for (int i = 0; i < 4; ++i)
                C[(size_t)(r0 + i) * K_DIM + col] = acc[mi][ni][i] + bv;
        }
    }
}

// ---------------------------------------------------------------------------
extern "C" void kernel_launch(void* const* d_in, const int* in_sizes, int n_in,
                              void* d_out, int out_size, void* d_ws, size_t ws_size,
                              hipStream_t stream)
{
    (void)in_sizes; (void)n_in; (void)out_size; (void)ws_size;

    const float* x    = (const float*)d_in[0];
    KronPtrs P;
    for (int i = 0; i < 8; ++i) {
        P.a[i] = (const float*)d_in[1 + i];
        P.b[i] = (const float*)d_in[9 + i];
    }
    const float* bias = (const float*)d_in[17];

    __hip_bfloat16* Wb = (__hip_bfloat16*)d_ws;                               // 32 MiB
    __hip_bfloat16* Xb = (__hip_bfloat16*)((char*)d_ws +
                          (size_t)K_DIM * K_DIM * sizeof(__hip_bfloat16));    // 32 MiB
    float* y = (float*)d_out;

    prologue_kernel<<<12288, 256, 0, stream>>>(P, x, Wb, Xb);

    dim3 grid(32, 32);
    gemm_kernel<<<grid, 256, 0, stream>>>(Wb, Xb, bias, y);
}

// Round 3
// 292.489 us; speedup vs baseline: 1.0722x; 1.0386x over previous
//
#include <hip/hip_runtime.h>
#include <hip/hip_bf16.h>
#include <cstdint>
#include <cstddef>

#define K_DIM 4096

typedef __bf16 bf16x8 __attribute__((ext_vector_type(8)));
typedef float  f32x16 __attribute__((ext_vector_type(16)));
typedef unsigned short ushort8 __attribute__((ext_vector_type(8)));

struct KronPtrs { const float* a[8]; const float* b[8]; };

// ---------------------------------------------------------------------------
// Fused prologue (unchanged from R2 — ~22 µs, write-bound).
//   Blocks [0, 8192):      x fp32 -> bf16   (8 elems / thread)
//   Blocks [8192, 12288):  build one row of W = sum_k kron(a_k,b_k) * s
// ---------------------------------------------------------------------------
__global__ __launch_bounds__(256) void prologue_kernel(
        KronPtrs P,
        const float* __restrict__ x,
        __hip_bfloat16* __restrict__ Wb,
        __hip_bfloat16* __restrict__ Xb)
{
    __shared__ __align__(16) float sa[1080];
    __shared__ __align__(16) float sb[1080];

    const int tid = threadIdx.x;

    if (blockIdx.x < 8192) {
        const size_t t = (size_t)blockIdx.x * 256 + tid;
        const size_t o = t * 8;
        const float4 v0 = *(const float4*)(x + o);
        const float4 v1 = *(const float4*)(x + o + 4);
        union { __hip_bfloat16 h[8]; ushort8 v; } u;
        u.h[0] = __float2bfloat16(v0.x);
        u.h[1] = __float2bfloat16(v0.y);
        u.h[2] = __float2bfloat16(v0.z);
        u.h[3] = __float2bfloat16(v0.w);
        u.h[4] = __float2bfloat16(v1.x);
        u.h[5] = __float2bfloat16(v1.y);
        u.h[6] = __float2bfloat16(v1.z);
        u.h[7] = __float2bfloat16(v1.w);
        *(ushort8*)(void*)(Xb + o) = u.v;
        return;
    }

    const int row = blockIdx.x - 8192;

#define STAGE(IDX, MA, LB, OA, OB)                                             \
    {                                                                          \
        const int mb_ = 1 << (LB);                                             \
        const float* ap = P.a[IDX] + (size_t)(row >> (LB)) * (MA);             \
        const float* bp = P.b[IDX] + (size_t)(row & (mb_ - 1)) * mb_;          \
        for (int i = tid; i < (MA); i += 256) sa[(OA) + i] = ap[i];            \
        for (int i = tid; i < mb_;  i += 256) sb[(OB) + i] = bp[i];            \
    }

    STAGE(0,  64, 6,   0,    0)
    STAGE(1,  64, 6,  64,   64)
    STAGE(2,  32, 7, 128,  128)
    STAGE(3, 128, 5, 160,  256)
    STAGE(4,  16, 8, 288,  288)
    STAGE(5, 256, 4, 304,  544)
    STAGE(6,   8, 9, 560,  560)
    STAGE(7, 512, 3, 568, 1072)
#undef STAGE

    __syncthreads();

    const float s = 0.17677669529663687f;  // 1 / (2*sqrt(8))
    const int q0 = tid << 4;

#pragma unroll
    for (int g = 0; g < 2; ++g) {
        const int q8 = q0 + (g << 3);
        float acc[8] = {0.f,0.f,0.f,0.f,0.f,0.f,0.f,0.f};

#define KTERM(LB, OA, OB)                                                      \
    {                                                                          \
        const int mb_   = 1 << (LB);                                           \
        const float av  = sa[(OA) + (q8 >> (LB))];                             \
        const float* bp = sb + (OB) + (q8 & (mb_ - 1));                        \
        const float4 x0 = *(const float4*)(bp);                                \
        const float4 x1 = *(const float4*)(bp + 4);                            \
        acc[0] += av * x0.x; acc[1] += av * x0.y;                              \
        acc[2] += av * x0.z; acc[3] += av * x0.w;                              \
        acc[4] += av * x1.x; acc[5] += av * x1.y;                              \
        acc[6] += av * x1.z; acc[7] += av * x1.w;                              \
    }

        KTERM(6,   0,    0)
        KTERM(6,  64,   64)
        KTERM(7, 128,  128)
        KTERM(5, 160,  256)
        KTERM(8, 288,  288)
        KTERM(4, 304,  544)
        KTERM(9, 560,  560)
        KTERM(3, 568, 1072)
#undef KTERM

        union { __hip_bfloat16 h[8]; ushort8 v; } u;
#pragma unroll
        for (int i = 0; i < 8; ++i) u.h[i] = __float2bfloat16(acc[i] * s);
        *(ushort8*)(void*)(Wb + (size_t)row * K_DIM + q8) = u.v;
    }
}

// ---------------------------------------------------------------------------
// GEMM: C[m][n] = sum_k Wb[m][k] * Xb[n][k] + bias[n]   (C = W @ X^T)
// R3: switch to v_mfma_f32_32x32x16_bf16 (8.07 cyc per 32k FLOP vs 4.85 per
// 16k -> ~15% less matrix-pipe time, half the MFMA issue slots) with 2x2
// 32x32 tiles per wave (same 64x64 wave tile, 128x128 block, BK=64).
// Fragment mapping (m74/m101, end-to-end verified): A/B lane -> row=lane&31,
// k=(lane>>5)*8+j; C/D col=lane&31, row=(reg&3)+8*(reg>>2)+4*(lane>>5).
// Staging addresses strength-reduced to loop-carried pointers (+128 B/iter).
// ---------------------------------------------------------------------------
__device__ __forceinline__ void gload_lds16(const void* g, void* l)
{
    __builtin_amdgcn_global_load_lds((const __attribute__((address_space(1))) void*)g,
                                     (__attribute__((address_space(3))) void*)l,
                                     16, 0, 0);
}

__global__ __launch_bounds__(256) void gemm_kernel(
        const __hip_bfloat16* __restrict__ Wb,
        const __hip_bfloat16* __restrict__ Xb,
        const float* __restrict__ bias,
        float* __restrict__ C)
{
    __shared__ __align__(16) __hip_bfloat16 lsA[128 * 64];
    __shared__ __align__(16) __hip_bfloat16 lsB[128 * 64];

    const int tid  = threadIdx.x;
    const int lane = tid & 63;
    const int wid  = tid >> 6;
    const int wr   = wid >> 1;   // wave row 0..1
    const int wc   = wid & 1;    // wave col 0..1

    const int bm = blockIdx.y << 7;
    const int bn = blockIdx.x << 7;

    // Staging swizzle: within a 1KB chunk (8 rows x 128B), physical 16B-chunk
    // p of row r holds LOGICAL chunk p ^ (r&7); lane L writes (row L>>3,
    // phys chunk L&7), so it must fetch logical chunk (L&7)^(L>>3).
    const int sr = lane >> 3;
    const int lc = (lane & 7) ^ sr;

    const __hip_bfloat16* gA[4];
    const __hip_bfloat16* gB[4];
#pragma unroll
    for (int i = 0; i < 4; ++i) {
        const int c = (wid << 2) + i;             // 8-row chunk 0..15
        gA[i] = Wb + (size_t)(bm + c * 8 + sr) * K_DIM + lc * 8;
        gB[i] = Xb + (size_t)(bn + c * 8 + sr) * K_DIM + lc * 8;
    }

    f32x16 acc[2][2];
#pragma unroll
    for (int i = 0; i < 2; ++i)
#pragma unroll
        for (int j = 0; j < 2; ++j) acc[i][j] = (f32x16)(0.0f);

    const int rl = lane & 31;   // fragment row within 32x32 tile
    const int hk = lane >> 5;   // k-half (0: k 0..7, 1: k 8..15 of a k16 step)
    const int fx = lane & 7;    // read-side swizzle xor (= frag row & 7)

    for (int k0 = 0; k0 < K_DIM; k0 += 64) {
#pragma unroll
        for (int i = 0; i < 4; ++i) {
            const int c = (wid << 2) + i;
            gload_lds16(gA[i], lsA + c * 512);
            gload_lds16(gB[i], lsB + c * 512);
            gA[i] += 64;
            gB[i] += 64;
        }
        __syncthreads();

#pragma unroll
        for (int s = 0; s < 4; ++s) {            // 4 k-steps of 16
            const int lch = (s << 1) + hk;       // logical 8-elem k-chunk 0..7
            const int pch = lch ^ fx;            // physical chunk in LDS row
            bf16x8 af[2], bfv[2];
#pragma unroll
            for (int mi = 0; mi < 2; ++mi) {
                const int r = (wr << 6) + (mi << 5) + rl;
                af[mi] = *(const bf16x8*)(const void*)(lsA + r * 64 + pch * 8);
            }
#pragma unroll
            for (int ni = 0; ni < 2; ++ni) {
                const int r = (wc << 6) + (ni << 5) + rl;
                bfv[ni] = *(const bf16x8*)(const void*)(lsB + r * 64 + pch * 8);
            }
#pragma unroll
            for (int mi = 0; mi < 2; ++mi)
#pragma unroll
                for (int ni = 0; ni < 2; ++ni)
                    acc[mi][ni] = __builtin_amdgcn_mfma_f32_32x32x16_bf16(
                        af[mi], bfv[ni], acc[mi][ni], 0, 0, 0);
        }
        __syncthreads();
    }

    // Epilogue: C/D col = lane&31, row = (reg&3) + 8*(reg>>2) + 4*(lane>>5)
#pragma unroll
    for (int ni = 0; ni < 2; ++ni) {
        const int col = bn + (wc << 6) + (ni << 5) + rl;
        const float bv = bias[col];
#pragma unroll
        for (int mi = 0; mi < 2; ++mi) {
            const int rbase = bm + (wr << 6) + (mi << 5) + (hk << 2);
#pragma unroll
            for (int reg = 0; reg < 16; ++reg) {
                const int row = rbase + (reg & 3) + ((reg >> 2) << 3);
                C[(size_t)row * K_DIM + col] = acc[mi][ni][reg] + bv;
            }
        }
    }
}

// ---------------------------------------------------------------------------
extern "C" void kernel_launch(void* const* d_in, const int* in_sizes, int n_in,
                              void* d_out, int out_size, void* d_ws, size_t ws_size,
                              hipStream_t stream)
{
    (void)in_sizes; (void)n_in; (void)out_size; (void)ws_size;

    const float* x    = (const float*)d_in[0];
    KronPtrs P;
    for (int i = 0; i < 8; ++i) {
        P.a[i] = (const float*)d_in[1 + i];
        P.b[i] = (const float*)d_in[9 + i];
    }
    const float* bias = (const float*)d_in[17];

    __hip_bfloat16* Wb = (__hip_bfloat16*)d_ws;                               // 32 MiB
    __hip_bfloat16* Xb = (__hip_bfloat16*)((char*)d_ws +
                          (size_t)K_DIM * K_DIM * sizeof(__hip_bfloat16));    // 32 MiB
    float* y = (float*)d_out;

    prologue_kernel<<<12288, 256, 0, stream>>>(P, x, Wb, Xb);

    dim3 grid(32, 32);
    gemm_kernel<<<grid, 256, 0, stream>>>(Wb, Xb, bias, y);
}

// Round 4
// 288.832 us; speedup vs baseline: 1.0858x; 1.0127x over previous
//
#include <hip/hip_runtime.h>
#include <hip/hip_bf16.h>
#include <cstdint>
#include <cstddef>

#define K_DIM 4096

typedef __bf16 bf16x8 __attribute__((ext_vector_type(8)));
typedef float  f32x4  __attribute__((ext_vector_type(4)));
typedef unsigned short ushort8 __attribute__((ext_vector_type(8)));

struct KronPtrs { const float* a[8]; const float* b[8]; };

// ---------------------------------------------------------------------------
// Fused prologue (unchanged from R2 — write-bound, ~22 µs).
// ---------------------------------------------------------------------------
__global__ __launch_bounds__(256) void prologue_kernel(
        KronPtrs P,
        const float* __restrict__ x,
        __hip_bfloat16* __restrict__ Wb,
        __hip_bfloat16* __restrict__ Xb)
{
    __shared__ __align__(16) float sa[1080];
    __shared__ __align__(16) float sb[1080];

    const int tid = threadIdx.x;

    if (blockIdx.x < 8192) {
        const size_t t = (size_t)blockIdx.x * 256 + tid;
        const size_t o = t * 8;
        const float4 v0 = *(const float4*)(x + o);
        const float4 v1 = *(const float4*)(x + o + 4);
        union { __hip_bfloat16 h[8]; ushort8 v; } u;
        u.h[0] = __float2bfloat16(v0.x);
        u.h[1] = __float2bfloat16(v0.y);
        u.h[2] = __float2bfloat16(v0.z);
        u.h[3] = __float2bfloat16(v0.w);
        u.h[4] = __float2bfloat16(v1.x);
        u.h[5] = __float2bfloat16(v1.y);
        u.h[6] = __float2bfloat16(v1.z);
        u.h[7] = __float2bfloat16(v1.w);
        *(ushort8*)(void*)(Xb + o) = u.v;
        return;
    }

    const int row = blockIdx.x - 8192;

#define STAGE(IDX, MA, LB, OA, OB)                                             \
    {                                                                          \
        const int mb_ = 1 << (LB);                                             \
        const float* ap = P.a[IDX] + (size_t)(row >> (LB)) * (MA);             \
        const float* bp = P.b[IDX] + (size_t)(row & (mb_ - 1)) * mb_;          \
        for (int i = tid; i < (MA); i += 256) sa[(OA) + i] = ap[i];            \
        for (int i = tid; i < mb_;  i += 256) sb[(OB) + i] = bp[i];            \
    }

    STAGE(0,  64, 6,   0,    0)
    STAGE(1,  64, 6,  64,   64)
    STAGE(2,  32, 7, 128,  128)
    STAGE(3, 128, 5, 160,  256)
    STAGE(4,  16, 8, 288,  288)
    STAGE(5, 256, 4, 304,  544)
    STAGE(6,   8, 9, 560,  560)
    STAGE(7, 512, 3, 568, 1072)
#undef STAGE

    __syncthreads();

    const float s = 0.17677669529663687f;  // 1 / (2*sqrt(8))
    const int q0 = tid << 4;

#pragma unroll
    for (int g = 0; g < 2; ++g) {
        const int q8 = q0 + (g << 3);
        float acc[8] = {0.f,0.f,0.f,0.f,0.f,0.f,0.f,0.f};

#define KTERM(LB, OA, OB)                                                      \
    {                                                                          \
        const int mb_   = 1 << (LB);                                           \
        const float av  = sa[(OA) + (q8 >> (LB))];                             \
        const float* bp = sb + (OB) + (q8 & (mb_ - 1));                        \
        const float4 x0 = *(const float4*)(bp);                                \
        const float4 x1 = *(const float4*)(bp + 4);                            \
        acc[0] += av * x0.x; acc[1] += av * x0.y;                              \
        acc[2] += av * x0.z; acc[3] += av * x0.w;                              \
        acc[4] += av * x1.x; acc[5] += av * x1.y;                              \
        acc[6] += av * x1.z; acc[7] += av * x1.w;                              \
    }

        KTERM(6,   0,    0)
        KTERM(6,  64,   64)
        KTERM(7, 128,  128)
        KTERM(5, 160,  256)
        KTERM(8, 288,  288)
        KTERM(4, 304,  544)
        KTERM(9, 560,  560)
        KTERM(3, 568, 1072)
#undef KTERM

        union { __hip_bfloat16 h[8]; ushort8 v; } u;
#pragma unroll
        for (int i = 0; i < 8; ++i) u.h[i] = __float2bfloat16(acc[i] * s);
        *(ushort8*)(void*)(Wb + (size_t)row * K_DIM + q8) = u.v;
    }
}

// ---------------------------------------------------------------------------
// GEMM: C[m][n] = sum_k Wb[m][k] * Xb[n][k] + bias[n]   (C = W @ X^T)
// R4: 16x16x32 MFMA (the R1 read pattern — MEASURED 0 bank conflicts, vs the
// 32x32 pattern's +4 cyc per ds_read_b128) combined with R3's VALU wins:
// loop-carried staging pointers (+128 B/iter) and k0-invariant hoisted LDS
// read bases. 128x128 block, 4 waves, each 64x64 via 4x4 mfma 16x16x32.
// ---------------------------------------------------------------------------
__device__ __forceinline__ void gload_lds16(const void* g, void* l)
{
    __builtin_amdgcn_global_load_lds((const __attribute__((address_space(1))) void*)g,
                                     (__attribute__((address_space(3))) void*)l,
                                     16, 0, 0);
}

__global__ __launch_bounds__(256) void gemm_kernel(
        const __hip_bfloat16* __restrict__ Wb,
        const __hip_bfloat16* __restrict__ Xb,
        const float* __restrict__ bias,
        float* __restrict__ C)
{
    __shared__ __align__(16) __hip_bfloat16 lsA[128 * 64];
    __shared__ __align__(16) __hip_bfloat16 lsB[128 * 64];

    const int tid  = threadIdx.x;
    const int lane = tid & 63;
    const int wid  = tid >> 6;
    const int wr   = wid >> 1;   // wave row 0..1
    const int wc   = wid & 1;    // wave col 0..1

    const int bm = blockIdx.y << 7;
    const int bn = blockIdx.x << 7;

    // Staging swizzle: within a 1KB chunk (8 rows x 128B), physical 16B-chunk
    // p of row r holds LOGICAL chunk p ^ (r&7); lane L writes (row L>>3,
    // phys chunk L&7) -> it fetches logical chunk (L&7)^(L>>3).
    const int sr = lane >> 3;
    const int lc = (lane & 7) ^ sr;

    const __hip_bfloat16* gA[4];
    const __hip_bfloat16* gB[4];
#pragma unroll
    for (int i = 0; i < 4; ++i) {
        const int c = (wid << 2) + i;             // 8-row chunk 0..15
        gA[i] = Wb + (size_t)(bm + c * 8 + sr) * K_DIM + lc * 8;
        gB[i] = Xb + (size_t)(bn + c * 8 + sr) * K_DIM + lc * 8;
    }

    f32x4 acc[4][4];
#pragma unroll
    for (int i = 0; i < 4; ++i)
#pragma unroll
        for (int j = 0; j < 4; ++j) acc[i][j] = (f32x4)(0.0f);

    const int fr = lane & 15;   // fragment row within 16x16 tile
    const int fq = lane >> 4;   // quad 0..3 (selects 8-elem k-chunk)
    const int fx = lane & 7;    // read-side swizzle xor (= frag row & 7)

    // k0-invariant LDS read bases (element pointers; mi/ni become immediate
    // ds offsets of 2048 B).
    const __hip_bfloat16* aRd = lsA + ((wr << 6) + fr) * 64;
    const __hip_bfloat16* bRd = lsB + ((wc << 6) + fr) * 64;

    for (int k0 = 0; k0 < K_DIM; k0 += 64) {
#pragma unroll
        for (int i = 0; i < 4; ++i) {
            const int c = (wid << 2) + i;
            gload_lds16(gA[i], lsA + c * 512);
            gload_lds16(gB[i], lsB + c * 512);
            gA[i] += 64;
            gB[i] += 64;
        }
        __syncthreads();

#pragma unroll
        for (int kk = 0; kk < 2; ++kk) {
            const int pch = ((kk << 2) + fq) ^ fx;   // physical 16B chunk 0..7
            const int off = pch * 8;                 // element offset in row
            bf16x8 af[4], bfv[4];
#pragma unroll
            for (int mi = 0; mi < 4; ++mi)
                af[mi] = *(const bf16x8*)(const void*)(aRd + off + mi * 1024);
#pragma unroll
            for (int ni = 0; ni < 4; ++ni)
                bfv[ni] = *(const bf16x8*)(const void*)(bRd + off + ni * 1024);
#pragma unroll
            for (int mi = 0; mi < 4; ++mi)
#pragma unroll
                for (int ni = 0; ni < 4; ++ni)
                    acc[mi][ni] = __builtin_amdgcn_mfma_f32_16x16x32_bf16(
                        af[mi], bfv[ni], acc[mi][ni], 0, 0, 0);
        }
        __syncthreads();
    }

    // Epilogue: C/D layout col = lane&15, row = (lane>>4)*4 + reg
#pragma unroll
    for (int ni = 0; ni < 4; ++ni) {
        const int col = bn + (wc << 6) + (ni << 4) + fr;
        const float bv = bias[col];
#pragma unroll
        for (int mi = 0; mi < 4; ++mi) {
            const int r0 = bm + (wr << 6) + (mi << 4) + (fq << 2);
#pragma unroll
            for (int i = 0; i < 4; ++i)
                C[(size_t)(r0 + i) * K_DIM + col] = acc[mi][ni][i] + bv;
        }
    }
}

// ---------------------------------------------------------------------------
extern "C" void kernel_launch(void* const* d_in, const int* in_sizes, int n_in,
                              void* d_out, int out_size, void* d_ws, size_t ws_size,
                              hipStream_t stream)
{
    (void)in_sizes; (void)n_in; (void)out_size; (void)ws_size;

    const float* x    = (const float*)d_in[0];
    KronPtrs P;
    for (int i = 0; i < 8; ++i) {
        P.a[i] = (const float*)d_in[1 + i];
        P.b[i] = (const float*)d_in[9 + i];
    }
    const float* bias = (const float*)d_in[17];

    __hip_bfloat16* Wb = (__hip_bfloat16*)d_ws;                               // 32 MiB
    __hip_bfloat16* Xb = (__hip_bfloat16*)((char*)d_ws +
                          (size_t)K_DIM * K_DIM * sizeof(__hip_bfloat16));    // 32 MiB
    float* y = (float*)d_out;

    prologue_kernel<<<12288, 256, 0, stream>>>(P, x, Wb, Xb);

    dim3 grid(32, 32);
    gemm_kernel<<<grid, 256, 0, stream>>>(Wb, Xb, bias, y);
}